// Round 1
// baseline (527.979 us; speedup 1.0000x reference)
//
#include <hip/hip_runtime.h>
#include <math.h>

#define NN 32768
#define KK 16
#define DD 128
#define EPSV 1e-5f

// ---------------------------------------------------------------------------
// K1: g = h @ W1   [N,128] = [N,128]@[128,128]
// block 256 (4 waves), 16 rows/block (4 rows/wave). W1 + 16 h-rows in LDS.
// ---------------------------------------------------------------------------
__global__ __launch_bounds__(256) void k_g(const float* __restrict__ h,
                                           const float* __restrict__ W1,
                                           float* __restrict__ g) {
    extern __shared__ float smem[];
    float* W1s = smem;            // 128*128
    float* hs  = smem + DD * DD;  // 16*128
    const int t = threadIdx.x;
    for (int i = t; i < DD * DD; i += 256) W1s[i] = W1[i];
    const int r0 = blockIdx.x * 16;
    for (int i = t; i < 16 * DD; i += 256) hs[i] = h[r0 * DD + i];
    __syncthreads();
    const int w = t >> 6, lane = t & 63;
    float acc[4][2] = {};
    #pragma unroll 4
    for (int d = 0; d < DD; ++d) {
        float w1a = W1s[d * DD + lane];
        float w1b = W1s[d * DD + 64 + lane];
        #pragma unroll
        for (int r = 0; r < 4; ++r) {
            float hd = hs[(w * 4 + r) * DD + d];
            acc[r][0] += hd * w1a;
            acc[r][1] += hd * w1b;
        }
    }
    #pragma unroll
    for (int r = 0; r < 4; ++r) {
        int row = r0 + w * 4 + r;
        g[row * DD + lane]      = acc[r][0];
        g[row * DD + 64 + lane] = acc[r][1];
    }
}

// ---------------------------------------------------------------------------
// K2: per-node attention stats. One wave per node.
// att[n,k] = exp(-relu( sum_e relu(g[src,e]-g[n,e]+b1[e]) * W2[e] + b2 ))
// writes amean = mean_k att, amax = max_k att, amin = min_k att
// ---------------------------------------------------------------------------
__global__ __launch_bounds__(256) void k_att(const float* __restrict__ g,
                                             const int* __restrict__ nbr,
                                             const float* __restrict__ b1,
                                             const float* __restrict__ W2,
                                             const float* __restrict__ b2,
                                             float* __restrict__ amean,
                                             float* __restrict__ amaxv,
                                             float* __restrict__ aminv) {
    const int t = threadIdx.x;
    const int w = t >> 6, lane = t & 63;
    const int node = blockIdx.x * 4 + w;
    const float2 gd  = ((const float2*)(g + node * DD))[lane];
    const float2 b1v = ((const float2*)b1)[lane];
    const float2 w2v = ((const float2*)W2)[lane];
    const float b2s = b2[0];
    float asum = 0.f, amx = -1e30f, amn = 1e30f;
    #pragma unroll
    for (int k = 0; k < KK; ++k) {
        int src = nbr[node * KK + k];
        float2 gs = ((const float2*)(g + src * DD))[lane];
        float v = fmaxf(gs.x - gd.x + b1v.x, 0.f) * w2v.x
                + fmaxf(gs.y - gd.y + b1v.y, 0.f) * w2v.y;
        #pragma unroll
        for (int off = 32; off > 0; off >>= 1) v += __shfl_xor(v, off);
        float s = fmaxf(v + b2s, 0.f);
        float att = __expf(-s);
        asum += att;
        amx = fmaxf(amx, att);
        amn = fminf(amn, att);
    }
    if (lane == 0) {
        amean[node] = asum * (1.f / KK);
        amaxv[node] = amx;
        aminv[node] = amn;
    }
}

// ---------------------------------------------------------------------------
// K3: t = h + concat(mean_agg, max_agg) @ OW + Ob ; accumulate bn1 sums.
// block 512 (8 waves), 128 rows/block, OW in LDS (128 KB) + 8 KB reduce.
// ---------------------------------------------------------------------------
__global__ __launch_bounds__(512) void k_t(const float* __restrict__ h,
                                           const float* __restrict__ OW,
                                           const float* __restrict__ Ob,
                                           const float* __restrict__ amean,
                                           const float* __restrict__ amaxv,
                                           const float* __restrict__ aminv,
                                           float* __restrict__ tbuf,
                                           float* __restrict__ bnsum,
                                           float* __restrict__ bnsq) {
    extern __shared__ float smem[];
    float* OWs  = smem;               // 256*128
    float* red  = smem + 2 * DD * DD; // 8*128
    float* redq = red + 8 * DD;       // 8*128
    const int t = threadIdx.x;
    for (int i = t; i < 2 * DD * DD; i += 512) OWs[i] = OW[i];
    __syncthreads();
    const int w = t >> 6, lane = t & 63;
    const float ob0 = Ob[lane], ob1 = Ob[64 + lane];
    float bs0 = 0, bs1 = 0, bq0 = 0, bq1 = 0;
    for (int i = 0; i < 16; ++i) {
        int row = blockIdx.x * 128 + i * 8 + w;
        float h0 = h[row * DD + lane];
        float h1 = h[row * DD + 64 + lane];
        float am = amean[row], ax = amaxv[row], an = aminv[row];
        float m0 = am * h0;                        // mean_agg[lane]
        float m1 = am * h1;                        // mean_agg[64+lane]
        float m2 = (h0 >= 0.f ? ax : an) * h0;     // max_agg[lane]
        float m3 = (h1 >= 0.f ? ax : an) * h1;     // max_agg[64+lane]
        float acc0 = 0.f, acc1 = 0.f;
        #pragma unroll 8
        for (int e2 = 0; e2 < 64; ++e2) {
            float me = __shfl(m0, e2);
            acc0 += me * OWs[e2 * DD + lane];
            acc1 += me * OWs[e2 * DD + 64 + lane];
        }
        #pragma unroll 8
        for (int e2 = 0; e2 < 64; ++e2) {
            float me = __shfl(m1, e2);
            int e = 64 + e2;
            acc0 += me * OWs[e * DD + lane];
            acc1 += me * OWs[e * DD + 64 + lane];
        }
        #pragma unroll 8
        for (int e2 = 0; e2 < 64; ++e2) {
            float me = __shfl(m2, e2);
            int e = 128 + e2;
            acc0 += me * OWs[e * DD + lane];
            acc1 += me * OWs[e * DD + 64 + lane];
        }
        #pragma unroll 8
        for (int e2 = 0; e2 < 64; ++e2) {
            float me = __shfl(m3, e2);
            int e = 192 + e2;
            acc0 += me * OWs[e * DD + lane];
            acc1 += me * OWs[e * DD + 64 + lane];
        }
        float t0 = h0 + acc0 + ob0;
        float t1 = h1 + acc1 + ob1;
        tbuf[row * DD + lane]      = t0;
        tbuf[row * DD + 64 + lane] = t1;
        bs0 += t0; bq0 += t0 * t0;
        bs1 += t1; bq1 += t1 * t1;
    }
    red[w * DD + lane] = bs0;  red[w * DD + 64 + lane] = bs1;
    redq[w * DD + lane] = bq0; redq[w * DD + 64 + lane] = bq1;
    __syncthreads();
    if (t < DD) {
        float s = 0, q = 0;
        #pragma unroll
        for (int ww = 0; ww < 8; ++ww) { s += red[ww * DD + t]; q += redq[ww * DD + t]; }
        atomicAdd(&bnsum[t], s);
        atomicAdd(&bnsq[t], q);
    }
}

// ---------------------------------------------------------------------------
// K4: x = bn1(t) (in-place over tbuf), u = relu(x @ F1W + F1b)
// bn1 stats finalized on the fly from bnsum/bnsq. F1W in LDS (128 KB).
// ---------------------------------------------------------------------------
__global__ __launch_bounds__(512) void k_ffn1(float* __restrict__ tbuf,
                                              const float* __restrict__ F1W,
                                              const float* __restrict__ F1b,
                                              const float* __restrict__ bn_g,
                                              const float* __restrict__ bn_b,
                                              const float* __restrict__ bnsum,
                                              const float* __restrict__ bnsq,
                                              float* __restrict__ u) {
    extern __shared__ float smem[];
    float* F1Ws = smem;  // 128*256
    const int t = threadIdx.x;
    for (int i = t; i < DD * 2 * DD; i += 512) F1Ws[i] = F1W[i];
    __syncthreads();
    const int w = t >> 6, lane = t & 63;
    const float inv = 1.f / NN;
    float mu0 = bnsum[lane] * inv, mu1 = bnsum[64 + lane] * inv;
    float v0 = bnsq[lane] * inv - mu0 * mu0, v1 = bnsq[64 + lane] * inv - mu1 * mu1;
    float sc0 = bn_g[lane] * rsqrtf(v0 + EPSV), sc1 = bn_g[64 + lane] * rsqrtf(v1 + EPSV);
    float sh0 = bn_b[lane] - mu0 * sc0, sh1 = bn_b[64 + lane] - mu1 * sc1;
    const float fb0 = F1b[lane], fb1 = F1b[64 + lane];
    const float fb2 = F1b[128 + lane], fb3 = F1b[192 + lane];
    for (int i = 0; i < 16; ++i) {
        int row = blockIdx.x * 128 + i * 8 + w;
        float x0 = tbuf[row * DD + lane] * sc0 + sh0;
        float x1 = tbuf[row * DD + 64 + lane] * sc1 + sh1;
        tbuf[row * DD + lane]      = x0;   // x replaces t in-place
        tbuf[row * DD + 64 + lane] = x1;
        float a0 = 0, a1 = 0, a2 = 0, a3 = 0;
        #pragma unroll 8
        for (int d2 = 0; d2 < 64; ++d2) {
            float xd = __shfl(x0, d2);
            a0 += xd * F1Ws[d2 * 256 + lane];
            a1 += xd * F1Ws[d2 * 256 + 64 + lane];
            a2 += xd * F1Ws[d2 * 256 + 128 + lane];
            a3 += xd * F1Ws[d2 * 256 + 192 + lane];
        }
        #pragma unroll 8
        for (int d2 = 0; d2 < 64; ++d2) {
            float xd = __shfl(x1, d2);
            int d = 64 + d2;
            a0 += xd * F1Ws[d * 256 + lane];
            a1 += xd * F1Ws[d * 256 + 64 + lane];
            a2 += xd * F1Ws[d * 256 + 128 + lane];
            a3 += xd * F1Ws[d * 256 + 192 + lane];
        }
        u[row * 256 + lane]       = fmaxf(a0 + fb0, 0.f);
        u[row * 256 + 64 + lane]  = fmaxf(a1 + fb1, 0.f);
        u[row * 256 + 128 + lane] = fmaxf(a2 + fb2, 0.f);
        u[row * 256 + 192 + lane] = fmaxf(a3 + fb3, 0.f);
    }
}

// ---------------------------------------------------------------------------
// K5: z = x + u @ F2W + F2b (in-place over tbuf); accumulate bn2 sums.
// ---------------------------------------------------------------------------
__global__ __launch_bounds__(512) void k_ffn2(float* __restrict__ xz,
                                              const float* __restrict__ u,
                                              const float* __restrict__ F2W,
                                              const float* __restrict__ F2b,
                                              float* __restrict__ bnsum,
                                              float* __restrict__ bnsq) {
    extern __shared__ float smem[];
    float* F2Ws = smem;               // 256*128
    float* red  = smem + 2 * DD * DD;
    float* redq = red + 8 * DD;
    const int t = threadIdx.x;
    for (int i = t; i < 2 * DD * DD; i += 512) F2Ws[i] = F2W[i];
    __syncthreads();
    const int w = t >> 6, lane = t & 63;
    const float fb0 = F2b[lane], fb1 = F2b[64 + lane];
    float bs0 = 0, bs1 = 0, bq0 = 0, bq1 = 0;
    for (int i = 0; i < 16; ++i) {
        int row = blockIdx.x * 128 + i * 8 + w;
        float u0 = u[row * 256 + lane];
        float u1 = u[row * 256 + 64 + lane];
        float u2 = u[row * 256 + 128 + lane];
        float u3 = u[row * 256 + 192 + lane];
        float x0 = xz[row * DD + lane];
        float x1 = xz[row * DD + 64 + lane];
        float a0 = 0, a1 = 0;
        #pragma unroll 8
        for (int e2 = 0; e2 < 64; ++e2) {
            float ue = __shfl(u0, e2);
            a0 += ue * F2Ws[e2 * DD + lane];
            a1 += ue * F2Ws[e2 * DD + 64 + lane];
        }
        #pragma unroll 8
        for (int e2 = 0; e2 < 64; ++e2) {
            float ue = __shfl(u1, e2);
            int e = 64 + e2;
            a0 += ue * F2Ws[e * DD + lane];
            a1 += ue * F2Ws[e * DD + 64 + lane];
        }
        #pragma unroll 8
        for (int e2 = 0; e2 < 64; ++e2) {
            float ue = __shfl(u2, e2);
            int e = 128 + e2;
            a0 += ue * F2Ws[e * DD + lane];
            a1 += ue * F2Ws[e * DD + 64 + lane];
        }
        #pragma unroll 8
        for (int e2 = 0; e2 < 64; ++e2) {
            float ue = __shfl(u3, e2);
            int e = 192 + e2;
            a0 += ue * F2Ws[e * DD + lane];
            a1 += ue * F2Ws[e * DD + 64 + lane];
        }
        float z0 = x0 + a0 + fb0;
        float z1 = x1 + a1 + fb1;
        xz[row * DD + lane]      = z0;   // z replaces x in-place
        xz[row * DD + 64 + lane] = z1;
        bs0 += z0; bq0 += z0 * z0;
        bs1 += z1; bq1 += z1 * z1;
    }
    red[w * DD + lane] = bs0;  red[w * DD + 64 + lane] = bs1;
    redq[w * DD + lane] = bq0; redq[w * DD + 64 + lane] = bq1;
    __syncthreads();
    if (t < DD) {
        float s = 0, q = 0;
        #pragma unroll
        for (int ww = 0; ww < 8; ++ww) { s += red[ww * DD + t]; q += redq[ww * DD + t]; }
        atomicAdd(&bnsum[t], s);
        atomicAdd(&bnsq[t], q);
    }
}

// ---------------------------------------------------------------------------
// K6: out = bn2(z)  — elementwise, float2 per thread.
// ---------------------------------------------------------------------------
__global__ __launch_bounds__(256) void k_out(const float* __restrict__ z,
                                             const float* __restrict__ bnsum,
                                             const float* __restrict__ bnsq,
                                             const float* __restrict__ gam,
                                             const float* __restrict__ bet,
                                             float* __restrict__ out) {
    int idx = blockIdx.x * 256 + threadIdx.x;  // over N*64 float2's
    int c0 = (idx & 63) * 2;
    const float inv = 1.f / NN;
    float mu0 = bnsum[c0] * inv, mu1 = bnsum[c0 + 1] * inv;
    float v0 = bnsq[c0] * inv - mu0 * mu0, v1 = bnsq[c0 + 1] * inv - mu1 * mu1;
    float sc0 = gam[c0] * rsqrtf(v0 + EPSV), sc1 = gam[c0 + 1] * rsqrtf(v1 + EPSV);
    float sh0 = bet[c0] - mu0 * sc0, sh1 = bet[c0 + 1] - mu1 * sc1;
    float2 zv = ((const float2*)z)[idx];
    float2 ov;
    ov.x = zv.x * sc0 + sh0;
    ov.y = zv.y * sc1 + sh1;
    ((float2*)out)[idx] = ov;
}

// ---------------------------------------------------------------------------
extern "C" void kernel_launch(void* const* d_in, const int* in_sizes, int n_in,
                              void* d_out, int out_size, void* d_ws, size_t ws_size,
                              hipStream_t stream) {
    const float* h    = (const float*)d_in[0];
    const int*   nbr  = (const int*)d_in[1];
    const float* W1   = (const float*)d_in[2];
    const float* b1   = (const float*)d_in[3];
    const float* W2   = (const float*)d_in[4];
    const float* b2   = (const float*)d_in[5];
    const float* OW   = (const float*)d_in[6];
    const float* Ob   = (const float*)d_in[7];
    const float* bn1g = (const float*)d_in[8];
    const float* bn1b = (const float*)d_in[9];
    const float* F1W  = (const float*)d_in[10];
    const float* F1b  = (const float*)d_in[11];
    const float* F2W  = (const float*)d_in[12];
    const float* F2b  = (const float*)d_in[13];
    const float* bn2g = (const float*)d_in[14];
    const float* bn2b = (const float*)d_in[15];
    float* out = (float*)d_out;

    float* ws = (float*)d_ws;
    float* g      = ws;                         // N*128 (low half of region1)
    float* u      = ws;                         // N*256 (region1, reused after k_att)
    float* tbuf   = ws + (size_t)NN * 256;      // N*128 (t -> x -> z in-place)
    float* stats  = tbuf + (size_t)NN * DD;     // 512 floats
    float* bnsum1 = stats;
    float* bnsq1  = stats + 128;
    float* bnsum2 = stats + 256;
    float* bnsq2  = stats + 384;
    float* amean  = stats + 512;                // N
    float* amaxv  = amean + NN;                 // N
    float* aminv  = amaxv + NN;                 // N

    (void)hipMemsetAsync(stats, 0, 512 * sizeof(float), stream);

    k_g<<<NN / 16, 256, (DD * DD + 16 * DD) * 4, stream>>>(h, W1, g);
    k_att<<<NN / 4, 256, 0, stream>>>(g, nbr, b1, W2, b2, amean, amaxv, aminv);
    k_t<<<NN / 128, 512, (2 * DD * DD + 16 * DD) * 4, stream>>>(
        h, OW, Ob, amean, amaxv, aminv, tbuf, bnsum1, bnsq1);
    k_ffn1<<<NN / 128, 512, (2 * DD * DD) * 4, stream>>>(
        tbuf, F1W, F1b, bn1g, bn1b, bnsum1, bnsq1, u);
    k_ffn2<<<NN / 128, 512, (2 * DD * DD + 16 * DD) * 4, stream>>>(
        tbuf, u, F2W, F2b, bnsum2, bnsq2);
    k_out<<<NN * 64 / 256, 256, 0, stream>>>(tbuf, bnsum2, bnsq2, bn2g, bn2b, out);
}

// Round 3
// 147.681 us; speedup vs baseline: 3.5751x; 3.5751x over previous
//
#include <hip/hip_runtime.h>
#include <math.h>

#define NN 32768
#define KK 16
#define DD 128
#define EPSV 1e-5f

typedef __attribute__((ext_vector_type(8))) short bf16x8;
typedef __attribute__((ext_vector_type(4))) float f32x4;

__device__ __forceinline__ unsigned short f2bf(float x) {
    unsigned u; __builtin_memcpy(&u, &x, 4);
    u += 0x7fffu + ((u >> 16) & 1u);          // RNE (finite inputs)
    return (unsigned short)(u >> 16);
}

#define MFMA16(a, b, c) __builtin_amdgcn_mfma_f32_16x16x32_bf16((a), (b), (c), 0, 0, 0)

// ---------------------------------------------------------------------------
// Weight prep: convert 4 weight matrices to bf16 in B-fragment order.
// Frag (s,c,lane l): elems j=0..7 = B[32s + 8*(l>>4) + j][16c + (l&15)],
// stored at out[((s*NT + c)*64 + l)*8 + j].
// Ranges: W1 K128 N128 (2048 thr) | OW K256 N128 (4096) | F1W K128 N256 (4096)
//         | F2W K256 N128 (4096)  -> 14336 threads.
// ---------------------------------------------------------------------------
__global__ __launch_bounds__(256) void k_prep_w4(const float* __restrict__ W1,
                                                 const float* __restrict__ OW,
                                                 const float* __restrict__ F1W,
                                                 const float* __restrict__ F2W,
                                                 short* __restrict__ w1b,
                                                 short* __restrict__ owb,
                                                 short* __restrict__ f1wb,
                                                 short* __restrict__ f2wb) {
    int tid = blockIdx.x * 256 + threadIdx.x;
    const float* W; short* out; int Ncol; int base;
    if (tid < 2048)       { W = W1;  out = w1b;  Ncol = 128; base = 0; }
    else if (tid < 6144)  { W = OW;  out = owb;  Ncol = 128; base = 2048; }
    else if (tid < 10240) { W = F1W; out = f1wb; Ncol = 256; base = 6144; }
    else if (tid < 14336) { W = F2W; out = f2wb; Ncol = 128; base = 10240; }
    else return;
    int t = tid - base;
    int l = t & 63, sc = t >> 6;
    int NT = Ncol >> 4;
    int c = sc % NT, s = sc / NT;
    int col = c * 16 + (l & 15);
    int k0 = s * 32 + (l >> 4) * 8;
    bf16x8 v;
    #pragma unroll
    for (int j = 0; j < 8; ++j) v[j] = (short)f2bf(W[(size_t)(k0 + j) * Ncol + col]);
    *(bf16x8*)(out + (size_t)t * 8) = v;
}

// ---------------------------------------------------------------------------
// K1: g = h @ W1 (fp32 out). 4 waves x 32 rows, 256 blocks, no LDS.
// ---------------------------------------------------------------------------
__global__ __launch_bounds__(256) void k_g(const float* __restrict__ h,
                                           const short* __restrict__ w1b,
                                           float* __restrict__ g) {
    const int t = threadIdx.x, w = t >> 6, l = t & 63;
    const int g16 = l >> 4, r16 = l & 15;
    const int rowbase = blockIdx.x * 128 + w * 32;
    f32x4 acc[2][8];
    #pragma unroll
    for (int rt = 0; rt < 2; ++rt)
        #pragma unroll
        for (int c = 0; c < 8; ++c) acc[rt][c] = (f32x4){0.f, 0.f, 0.f, 0.f};
    for (int s = 0; s < 4; ++s) {
        bf16x8 a[2];
        #pragma unroll
        for (int rt = 0; rt < 2; ++rt) {
            int row = rowbase + rt * 16 + r16;
            const float* hp = h + (size_t)row * DD + s * 32 + g16 * 8;
            float4 x0 = *(const float4*)hp;
            float4 x1 = *(const float4*)(hp + 4);
            bf16x8 af;
            af[0] = (short)f2bf(x0.x); af[1] = (short)f2bf(x0.y);
            af[2] = (short)f2bf(x0.z); af[3] = (short)f2bf(x0.w);
            af[4] = (short)f2bf(x1.x); af[5] = (short)f2bf(x1.y);
            af[6] = (short)f2bf(x1.z); af[7] = (short)f2bf(x1.w);
            a[rt] = af;
        }
        #pragma unroll
        for (int c = 0; c < 8; ++c) {
            bf16x8 b = *(const bf16x8*)(w1b + ((size_t)(s * 8 + c) * 64 + l) * 8);
            acc[0][c] = MFMA16(a[0], b, acc[0][c]);
            acc[1][c] = MFMA16(a[1], b, acc[1][c]);
        }
    }
    #pragma unroll
    for (int rt = 0; rt < 2; ++rt)
        #pragma unroll
        for (int c = 0; c < 8; ++c)
            #pragma unroll
            for (int j = 0; j < 4; ++j) {
                int row = rowbase + rt * 16 + g16 * 4 + j;
                g[(size_t)row * DD + c * 16 + r16] = acc[rt][c][j];
            }
}

// ---------------------------------------------------------------------------
// K2: per-node attention stats (one wave per node), fp32 g.
// ---------------------------------------------------------------------------
__global__ __launch_bounds__(256) void k_att(const float* __restrict__ g,
                                             const int* __restrict__ nbr,
                                             const float* __restrict__ b1,
                                             const float* __restrict__ W2,
                                             const float* __restrict__ b2,
                                             float* __restrict__ amean,
                                             float* __restrict__ amaxv,
                                             float* __restrict__ aminv) {
    const int t = threadIdx.x;
    const int w = t >> 6, lane = t & 63;
    const int node = blockIdx.x * 4 + w;
    const float2 gd  = ((const float2*)(g + (size_t)node * DD))[lane];
    const float2 b1v = ((const float2*)b1)[lane];
    const float2 w2v = ((const float2*)W2)[lane];
    const float b2s = b2[0];
    float asum = 0.f, amx = -1e30f, amn = 1e30f;
    #pragma unroll
    for (int k = 0; k < KK; ++k) {
        int src = nbr[node * KK + k];
        float2 gs = ((const float2*)(g + (size_t)src * DD))[lane];
        float v = fmaxf(gs.x - gd.x + b1v.x, 0.f) * w2v.x
                + fmaxf(gs.y - gd.y + b1v.y, 0.f) * w2v.y;
        #pragma unroll
        for (int off = 32; off > 0; off >>= 1) v += __shfl_xor(v, off);
        float s = fmaxf(v + b2s, 0.f);
        float att = __expf(-s);
        asum += att;
        amx = fmaxf(amx, att);
        amn = fminf(amn, att);
    }
    if (lane == 0) {
        amean[node] = asum * (1.f / KK);
        amaxv[node] = amx;
        aminv[node] = amn;
    }
}

// ---------------------------------------------------------------------------
// K3: mb[row] = [ am*h[row] || (h>=0?ax:an)*h[row] ]  as bf16 [N,256].
// ---------------------------------------------------------------------------
__global__ __launch_bounds__(256) void k_mb(const float* __restrict__ h,
                                            const float* __restrict__ amean,
                                            const float* __restrict__ amaxv,
                                            const float* __restrict__ aminv,
                                            short* __restrict__ mb) {
    int tid = blockIdx.x * 256 + threadIdx.x;   // N*16 threads
    int row = tid >> 4, k0 = (tid & 15) * 8;
    float am = amean[row], ax = amaxv[row], an = aminv[row];
    const float* hp = h + (size_t)row * DD + k0;
    float4 x0 = *(const float4*)hp;
    float4 x1 = *(const float4*)(hp + 4);
    float v[8] = {x0.x, x0.y, x0.z, x0.w, x1.x, x1.y, x1.z, x1.w};
    bf16x8 m0, m1;
    #pragma unroll
    for (int j = 0; j < 8; ++j) {
        m0[j] = (short)f2bf(am * v[j]);
        m1[j] = (short)f2bf((v[j] >= 0.f ? ax : an) * v[j]);
    }
    *(bf16x8*)(mb + (size_t)row * 256 + k0) = m0;
    *(bf16x8*)(mb + (size_t)row * 256 + 128 + k0) = m1;
}

// ---------------------------------------------------------------------------
// K4: t = h + mb @ OW + Ob  (pure GEMM [N,256]@[256,128], fp32 epilogue)
// ---------------------------------------------------------------------------
__global__ __launch_bounds__(256) void k_t(const short* __restrict__ mb,
                                           const short* __restrict__ owb,
                                           const float* __restrict__ h,
                                           const float* __restrict__ Ob,
                                           float* __restrict__ tbuf) {
    const int t = threadIdx.x, w = t >> 6, l = t & 63;
    const int g16 = l >> 4, r16 = l & 15;
    const int rowbase = blockIdx.x * 128 + w * 32;
    f32x4 acc[2][8];
    #pragma unroll
    for (int rt = 0; rt < 2; ++rt)
        #pragma unroll
        for (int c = 0; c < 8; ++c) acc[rt][c] = (f32x4){0.f, 0.f, 0.f, 0.f};
    for (int s = 0; s < 8; ++s) {
        bf16x8 a[2];
        #pragma unroll
        for (int rt = 0; rt < 2; ++rt)
            a[rt] = *(const bf16x8*)(mb + (size_t)(rowbase + rt * 16 + r16) * 256 + s * 32 + g16 * 8);
        #pragma unroll
        for (int c = 0; c < 8; ++c) {
            bf16x8 b = *(const bf16x8*)(owb + ((size_t)(s * 8 + c) * 64 + l) * 8);
            acc[0][c] = MFMA16(a[0], b, acc[0][c]);
            acc[1][c] = MFMA16(a[1], b, acc[1][c]);
        }
    }
    #pragma unroll
    for (int rt = 0; rt < 2; ++rt)
        #pragma unroll
        for (int c = 0; c < 8; ++c) {
            float ob = Ob[c * 16 + r16];
            #pragma unroll
            for (int j = 0; j < 4; ++j) {
                int row = rowbase + rt * 16 + g16 * 4 + j;
                size_t idx = (size_t)row * DD + c * 16 + r16;
                tbuf[idx] = h[idx] + acc[rt][c][j] + ob;
            }
        }
}

// ---------------------------------------------------------------------------
// Column sums + sumsq over a [N,128] fp32 matrix (for BN stats).
// ---------------------------------------------------------------------------
__global__ __launch_bounds__(256) void k_bnstats(const float* __restrict__ src,
                                                 float* __restrict__ bnsum,
                                                 float* __restrict__ bnsq) {
    __shared__ float red[2][128], redq[2][128];
    int t = threadIdx.x;
    int c = t & 127, half = t >> 7;
    int r0 = blockIdx.x * 128 + half * 64;
    float s = 0.f, q = 0.f;
    for (int i = 0; i < 64; ++i) {
        float v = src[(size_t)(r0 + i) * DD + c];
        s += v; q += v * v;
    }
    red[half][c] = s; redq[half][c] = q;
    __syncthreads();
    if (t < 128) {
        atomicAdd(&bnsum[t], red[0][t] + red[1][t]);
        atomicAdd(&bnsq[t],  redq[0][t] + redq[1][t]);
    }
}

// ---------------------------------------------------------------------------
// K5: u = relu(bn1(t) @ F1W + F1b) as bf16 [N,256].
// 8 waves: (rowtile of 32) x (coltile of 128). bn1 applied on the fly.
// ---------------------------------------------------------------------------
__global__ __launch_bounds__(512) void k_ffn1(const float* __restrict__ tbuf,
                                              const short* __restrict__ f1wb,
                                              const float* __restrict__ F1b,
                                              const float* __restrict__ bn_g,
                                              const float* __restrict__ bn_b,
                                              const float* __restrict__ bnsum,
                                              const float* __restrict__ bnsq,
                                              short* __restrict__ u) {
    const int t = threadIdx.x, w = t >> 6, l = t & 63;
    const int g16 = l >> 4, r16 = l & 15;
    const int ct = w & 1, rw = w >> 1;
    const int rowbase = blockIdx.x * 128 + rw * 32;
    const float inv = 1.f / NN;
    f32x4 acc[2][8];
    #pragma unroll
    for (int rt = 0; rt < 2; ++rt)
        #pragma unroll
        for (int c = 0; c < 8; ++c) acc[rt][c] = (f32x4){0.f, 0.f, 0.f, 0.f};
    for (int s = 0; s < 4; ++s) {
        int k0 = s * 32 + g16 * 8;
        float4 s0 = *(const float4*)(bnsum + k0), s1 = *(const float4*)(bnsum + k0 + 4);
        float4 q0 = *(const float4*)(bnsq + k0),  q1 = *(const float4*)(bnsq + k0 + 4);
        float4 gg0 = *(const float4*)(bn_g + k0), gg1 = *(const float4*)(bn_g + k0 + 4);
        float4 bb0 = *(const float4*)(bn_b + k0), bb1 = *(const float4*)(bn_b + k0 + 4);
        float sm[8] = {s0.x, s0.y, s0.z, s0.w, s1.x, s1.y, s1.z, s1.w};
        float sq[8] = {q0.x, q0.y, q0.z, q0.w, q1.x, q1.y, q1.z, q1.w};
        float gm[8] = {gg0.x, gg0.y, gg0.z, gg0.w, gg1.x, gg1.y, gg1.z, gg1.w};
        float bt[8] = {bb0.x, bb0.y, bb0.z, bb0.w, bb1.x, bb1.y, bb1.z, bb1.w};
        float scv[8], shv[8];
        #pragma unroll
        for (int j = 0; j < 8; ++j) {
            float mu = sm[j] * inv;
            float var = sq[j] * inv - mu * mu;
            scv[j] = gm[j] * rsqrtf(var + EPSV);
            shv[j] = bt[j] - mu * scv[j];
        }
        bf16x8 a[2];
        #pragma unroll
        for (int rt = 0; rt < 2; ++rt) {
            int row = rowbase + rt * 16 + r16;
            const float* tp = tbuf + (size_t)row * DD + k0;
            float4 x0 = *(const float4*)tp, x1 = *(const float4*)(tp + 4);
            float v[8] = {x0.x, x0.y, x0.z, x0.w, x1.x, x1.y, x1.z, x1.w};
            bf16x8 af;
            #pragma unroll
            for (int j = 0; j < 8; ++j) af[j] = (short)f2bf(v[j] * scv[j] + shv[j]);
            a[rt] = af;
        }
        #pragma unroll
        for (int cc = 0; cc < 8; ++cc) {
            int c = ct * 8 + cc;
            bf16x8 b = *(const bf16x8*)(f1wb + ((size_t)(s * 16 + c) * 64 + l) * 8);
            acc[0][cc] = MFMA16(a[0], b, acc[0][cc]);
            acc[1][cc] = MFMA16(a[1], b, acc[1][cc]);
        }
    }
    #pragma unroll
    for (int rt = 0; rt < 2; ++rt)
        #pragma unroll
        for (int cc = 0; cc < 8; ++cc) {
            int col = (ct * 8 + cc) * 16 + r16;
            float fb = F1b[col];
            #pragma unroll
            for (int j = 0; j < 4; ++j) {
                int row = rowbase + rt * 16 + g16 * 4 + j;
                u[(size_t)row * 256 + col] = (short)f2bf(fmaxf(acc[rt][cc][j] + fb, 0.f));
            }
        }
}

// ---------------------------------------------------------------------------
// K6: z = bn1(t) + u @ F2W + F2b  (in-place over tbuf; x recomputed in epi).
// ---------------------------------------------------------------------------
__global__ __launch_bounds__(256) void k_ffn2(const short* __restrict__ u,
                                              const short* __restrict__ f2wb,
                                              const float* __restrict__ F2b,
                                              const float* __restrict__ bn_g,
                                              const float* __restrict__ bn_b,
                                              const float* __restrict__ bnsum,
                                              const float* __restrict__ bnsq,
                                              float* __restrict__ tbuf) {
    const int t = threadIdx.x, w = t >> 6, l = t & 63;
    const int g16 = l >> 4, r16 = l & 15;
    const int rowbase = blockIdx.x * 128 + w * 32;
    const float inv = 1.f / NN;
    f32x4 acc[2][8];
    #pragma unroll
    for (int rt = 0; rt < 2; ++rt)
        #pragma unroll
        for (int c = 0; c < 8; ++c) acc[rt][c] = (f32x4){0.f, 0.f, 0.f, 0.f};
    for (int s = 0; s < 8; ++s) {
        bf16x8 a[2];
        #pragma unroll
        for (int rt = 0; rt < 2; ++rt)
            a[rt] = *(const bf16x8*)(u + (size_t)(rowbase + rt * 16 + r16) * 256 + s * 32 + g16 * 8);
        #pragma unroll
        for (int c = 0; c < 8; ++c) {
            bf16x8 b = *(const bf16x8*)(f2wb + ((size_t)(s * 8 + c) * 64 + l) * 8);
            acc[0][c] = MFMA16(a[0], b, acc[0][c]);
            acc[1][c] = MFMA16(a[1], b, acc[1][c]);
        }
    }
    #pragma unroll
    for (int rt = 0; rt < 2; ++rt)
        #pragma unroll
        for (int c = 0; c < 8; ++c) {
            int col = c * 16 + r16;
            float mu = bnsum[col] * inv;
            float var = bnsq[col] * inv - mu * mu;
            float sc = bn_g[col] * rsqrtf(var + EPSV);
            float sh = bn_b[col] - mu * sc;
            float fb = F2b[col];
            #pragma unroll
            for (int j = 0; j < 4; ++j) {
                int row = rowbase + rt * 16 + g16 * 4 + j;
                size_t idx = (size_t)row * DD + col;
                float x = tbuf[idx] * sc + sh;
                tbuf[idx] = x + acc[rt][c][j] + fb;
            }
        }
}

// ---------------------------------------------------------------------------
// K7: out = bn2(z) — elementwise, float2 per thread.
// ---------------------------------------------------------------------------
__global__ __launch_bounds__(256) void k_out(const float* __restrict__ z,
                                             const float* __restrict__ bnsum,
                                             const float* __restrict__ bnsq,
                                             const float* __restrict__ gam,
                                             const float* __restrict__ bet,
                                             float* __restrict__ out) {
    int idx = blockIdx.x * 256 + threadIdx.x;  // over N*64 float2's
    int c0 = (idx & 63) * 2;
    const float inv = 1.f / NN;
    float mu0 = bnsum[c0] * inv, mu1 = bnsum[c0 + 1] * inv;
    float v0 = bnsq[c0] * inv - mu0 * mu0, v1 = bnsq[c0 + 1] * inv - mu1 * mu1;
    float sc0 = gam[c0] * rsqrtf(v0 + EPSV), sc1 = gam[c0 + 1] * rsqrtf(v1 + EPSV);
    float sh0 = bet[c0] - mu0 * sc0, sh1 = bet[c0 + 1] - mu1 * sc1;
    float2 zv = ((const float2*)z)[idx];
    float2 ov;
    ov.x = zv.x * sc0 + sh0;
    ov.y = zv.y * sc1 + sh1;
    ((float2*)out)[idx] = ov;
}

// ---------------------------------------------------------------------------
extern "C" void kernel_launch(void* const* d_in, const int* in_sizes, int n_in,
                              void* d_out, int out_size, void* d_ws, size_t ws_size,
                              hipStream_t stream) {
    const float* h    = (const float*)d_in[0];
    const int*   nbr  = (const int*)d_in[1];
    const float* W1   = (const float*)d_in[2];
    const float* b1   = (const float*)d_in[3];
    const float* W2   = (const float*)d_in[4];
    const float* b2   = (const float*)d_in[5];
    const float* OW   = (const float*)d_in[6];
    const float* Ob   = (const float*)d_in[7];
    const float* bn1g = (const float*)d_in[8];
    const float* bn1b = (const float*)d_in[9];
    const float* F1W  = (const float*)d_in[10];
    const float* F1b  = (const float*)d_in[11];
    const float* F2W  = (const float*)d_in[12];
    const float* F2b  = (const float*)d_in[13];
    const float* bn2g = (const float*)d_in[14];
    const float* bn2b = (const float*)d_in[15];
    float* out = (float*)d_out;

    char* wsb = (char*)d_ws;
    // region1 (16 MB): g fp32 [N,128] -> mb bf16 [N,256] -> u bf16 [N,256]
    float* g   = (float*)wsb;
    short* mb  = (short*)wsb;
    short* u   = (short*)wsb;
    float* tbuf = (float*)(wsb + ((size_t)16 << 20));           // 16 MB fp32
    short* w1b  = (short*)(wsb + ((size_t)32 << 20));           // 32 KB
    short* owb  = w1b + 16384;                                  // 64 KB
    short* f1wb = owb + 32768;                                  // 64 KB
    short* f2wb = f1wb + 32768;                                 // 64 KB
    float* stats = (float*)(wsb + ((size_t)32 << 20) + 256 * 1024);
    float* bnsum1 = stats;
    float* bnsq1  = stats + 128;
    float* bnsum2 = stats + 256;
    float* bnsq2  = stats + 384;
    float* amean  = stats + 512;
    float* amaxv  = amean + NN;
    float* aminv  = amaxv + NN;

    (void)hipMemsetAsync(stats, 0, 512 * sizeof(float), stream);

    k_prep_w4<<<56, 256, 0, stream>>>(W1, OW, F1W, F2W, w1b, owb, f1wb, f2wb);
    k_g<<<NN / 128, 256, 0, stream>>>(h, w1b, g);
    k_att<<<NN / 4, 256, 0, stream>>>(g, nbr, b1, W2, b2, amean, amaxv, aminv);
    k_mb<<<NN * 16 / 256, 256, 0, stream>>>(h, amean, amaxv, aminv, mb);
    k_t<<<NN / 128, 256, 0, stream>>>(mb, owb, h, Ob, tbuf);
    k_bnstats<<<NN / 128, 256, 0, stream>>>(tbuf, bnsum1, bnsq1);
    k_ffn1<<<NN / 128, 512, 0, stream>>>(tbuf, f1wb, F1b, bn1g, bn1b, bnsum1, bnsq1, u);
    k_ffn2<<<NN / 128, 256, 0, stream>>>(u, f2wb, F2b, bn1g, bn1b, bnsum1, bnsq1, tbuf);
    k_bnstats<<<NN / 128, 256, 0, stream>>>(tbuf, bnsum2, bnsq2);
    k_out<<<NN * 64 / 256, 256, 0, stream>>>(tbuf, bnsum2, bnsq2, bn2g, bn2b, out);
}

// Round 5
// 131.784 us; speedup vs baseline: 4.0064x; 1.1206x over previous
//
#include <hip/hip_runtime.h>
#include <math.h>

#define NN 32768
#define KK 16
#define DD 128
#define EPSV 1e-5f

typedef __attribute__((ext_vector_type(8))) short bf16x8;
typedef __attribute__((ext_vector_type(4))) float f32x4;

__device__ __forceinline__ unsigned short f2bf(float x) {
    unsigned u; __builtin_memcpy(&u, &x, 4);
    u += 0x7fffu + ((u >> 16) & 1u);          // RNE (finite inputs)
    return (unsigned short)(u >> 16);
}
__device__ __forceinline__ float bf2f(unsigned short b) {
    unsigned u = ((unsigned)b) << 16; float f; __builtin_memcpy(&f, &u, 4); return f;
}

#define MFMA16(a, b, c) __builtin_amdgcn_mfma_f32_16x16x32_bf16((a), (b), (c), 0, 0, 0)

// ---------------------------------------------------------------------------
// Weight prep: 4 weight matrices -> bf16 B-fragment order; also zero stats.
// Frag (s,c,lane l): elems j=0..7 = B[32s + 8*(l>>4) + j][16c + (l&15)],
// stored at out[((s*NT + c)*64 + l)*8 + j].
// W1 K128N128 (2048 thr) | OW K256N128 (4096) | F1W K128N256 (4096)
// | F2W K256N128 (4096) | stats zero (512)  -> 14848 threads, 58 blocks.
// ---------------------------------------------------------------------------
__global__ __launch_bounds__(256) void k_prep_w4(const float* __restrict__ W1,
                                                 const float* __restrict__ OW,
                                                 const float* __restrict__ F1W,
                                                 const float* __restrict__ F2W,
                                                 short* __restrict__ w1b,
                                                 short* __restrict__ owb,
                                                 short* __restrict__ f1wb,
                                                 short* __restrict__ f2wb,
                                                 float* __restrict__ stats) {
    int tid = blockIdx.x * 256 + threadIdx.x;
    if (tid >= 14848) return;
    if (tid >= 14336) { stats[tid - 14336] = 0.f; return; }
    const float* W; short* out; int Ncol; int base;
    if (tid < 2048)       { W = W1;  out = w1b;  Ncol = 128; base = 0; }
    else if (tid < 6144)  { W = OW;  out = owb;  Ncol = 128; base = 2048; }
    else if (tid < 10240) { W = F1W; out = f1wb; Ncol = 256; base = 6144; }
    else                  { W = F2W; out = f2wb; Ncol = 128; base = 10240; }
    int t = tid - base;
    int l = t & 63, sc = t >> 6;
    int NT = Ncol >> 4;
    int c = sc % NT, s = sc / NT;
    int col = c * 16 + (l & 15);
    int k0 = s * 32 + (l >> 4) * 8;
    bf16x8 v;
    #pragma unroll
    for (int j = 0; j < 8; ++j) v[j] = (short)f2bf(W[(size_t)(k0 + j) * Ncol + col]);
    *(bf16x8*)(out + (size_t)t * 8) = v;
}

// ---------------------------------------------------------------------------
// K1: gb = bf16(h @ W1). 4 waves x 32 rows, 256 blocks, no LDS.
// ---------------------------------------------------------------------------
__global__ __launch_bounds__(256) void k_g(const float* __restrict__ h,
                                           const short* __restrict__ w1b,
                                           unsigned short* __restrict__ gb) {
    const int t = threadIdx.x, w = t >> 6, l = t & 63;
    const int g16 = l >> 4, r16 = l & 15;
    const int rowbase = blockIdx.x * 128 + w * 32;
    f32x4 acc[2][8];
    #pragma unroll
    for (int rt = 0; rt < 2; ++rt)
        #pragma unroll
        for (int c = 0; c < 8; ++c) acc[rt][c] = (f32x4){0.f, 0.f, 0.f, 0.f};
    for (int s = 0; s < 4; ++s) {
        bf16x8 a[2];
        #pragma unroll
        for (int rt = 0; rt < 2; ++rt) {
            int row = rowbase + rt * 16 + r16;
            const float* hp = h + (size_t)row * DD + s * 32 + g16 * 8;
            float4 x0 = *(const float4*)hp;
            float4 x1 = *(const float4*)(hp + 4);
            bf16x8 af;
            af[0] = (short)f2bf(x0.x); af[1] = (short)f2bf(x0.y);
            af[2] = (short)f2bf(x0.z); af[3] = (short)f2bf(x0.w);
            af[4] = (short)f2bf(x1.x); af[5] = (short)f2bf(x1.y);
            af[6] = (short)f2bf(x1.z); af[7] = (short)f2bf(x1.w);
            a[rt] = af;
        }
        #pragma unroll
        for (int c = 0; c < 8; ++c) {
            bf16x8 b = *(const bf16x8*)(w1b + ((size_t)(s * 8 + c) * 64 + l) * 8);
            acc[0][c] = MFMA16(a[0], b, acc[0][c]);
            acc[1][c] = MFMA16(a[1], b, acc[1][c]);
        }
    }
    #pragma unroll
    for (int rt = 0; rt < 2; ++rt)
        #pragma unroll
        for (int c = 0; c < 8; ++c)
            #pragma unroll
            for (int j = 0; j < 4; ++j) {
                int row = rowbase + rt * 16 + g16 * 4 + j;
                gb[(size_t)row * DD + c * 16 + r16] = f2bf(acc[rt][c][j]);
            }
}

// ---------------------------------------------------------------------------
// K2: per-node attention stats + mb write. One wave per node.
// att[k] = exp(-relu(sum_e relu(g[src,e]-g[n,e]+b1[e])*W2[e] + b2))
// mb[n] = [ mean_k(att)*h[n] || (h>=0?max_k:min_k att)*h[n] ] as bf16 [N,256]
// ---------------------------------------------------------------------------
__global__ __launch_bounds__(256) void k_att(const unsigned short* __restrict__ gb,
                                             const int* __restrict__ nbr,
                                             const float* __restrict__ b1,
                                             const float* __restrict__ W2,
                                             const float* __restrict__ b2,
                                             const float* __restrict__ h,
                                             unsigned short* __restrict__ mb) {
    const int t = threadIdx.x;
    const int w = t >> 6, lane = t & 63;
    const int node = blockIdx.x * 4 + w;
    ushort2 gdv = ((const ushort2*)(gb + (size_t)node * DD))[lane];
    const float gdx = bf2f(gdv.x), gdy = bf2f(gdv.y);
    const float2 b1v = ((const float2*)b1)[lane];
    const float2 w2v = ((const float2*)W2)[lane];
    const float b2s = b2[0];
    float asum = 0.f, amx = -1e30f, amn = 1e30f;
    #pragma unroll
    for (int k = 0; k < KK; ++k) {
        int src = nbr[node * KK + k];
        ushort2 gsv = ((const ushort2*)(gb + (size_t)src * DD))[lane];
        float v = fmaxf(bf2f(gsv.x) - gdx + b1v.x, 0.f) * w2v.x
                + fmaxf(bf2f(gsv.y) - gdy + b1v.y, 0.f) * w2v.y;
        #pragma unroll
        for (int off = 32; off > 0; off >>= 1) v += __shfl_xor(v, off);
        float s = fmaxf(v + b2s, 0.f);
        float att = __expf(-s);
        asum += att;
        amx = fmaxf(amx, att);
        amn = fminf(amn, att);
    }
    const float am = asum * (1.f / KK);
    float2 hv = ((const float2*)(h + (size_t)node * DD))[lane];
    ushort2 m0, m1;
    m0.x = f2bf(am * hv.x);
    m0.y = f2bf(am * hv.y);
    m1.x = f2bf((hv.x >= 0.f ? amx : amn) * hv.x);
    m1.y = f2bf((hv.y >= 0.f ? amx : amn) * hv.y);
    ((ushort2*)(mb + (size_t)node * 256))[lane] = m0;
    ((ushort2*)(mb + (size_t)node * 256 + 128))[lane] = m1;
}

// ---------------------------------------------------------------------------
// K3: t = h + mb @ OW + Ob (GEMM [N,256]@[256,128]); fused bn1 column sums.
// ---------------------------------------------------------------------------
__global__ __launch_bounds__(256) void k_t(const short* __restrict__ mb,
                                           const short* __restrict__ owb,
                                           const float* __restrict__ h,
                                           const float* __restrict__ Ob,
                                           float* __restrict__ tbuf,
                                           float* __restrict__ bnsum,
                                           float* __restrict__ bnsq) {
    __shared__ float sred[4 * 128], qred[4 * 128];
    const int t = threadIdx.x, w = t >> 6, l = t & 63;
    const int g16 = l >> 4, r16 = l & 15;
    const int rowbase = blockIdx.x * 128 + w * 32;
    f32x4 acc[2][8];
    #pragma unroll
    for (int rt = 0; rt < 2; ++rt)
        #pragma unroll
        for (int c = 0; c < 8; ++c) acc[rt][c] = (f32x4){0.f, 0.f, 0.f, 0.f};
    for (int s = 0; s < 8; ++s) {
        bf16x8 a[2];
        #pragma unroll
        for (int rt = 0; rt < 2; ++rt)
            a[rt] = *(const bf16x8*)(mb + (size_t)(rowbase + rt * 16 + r16) * 256 + s * 32 + g16 * 8);
        #pragma unroll
        for (int c = 0; c < 8; ++c) {
            bf16x8 b = *(const bf16x8*)(owb + ((size_t)(s * 8 + c) * 64 + l) * 8);
            acc[0][c] = MFMA16(a[0], b, acc[0][c]);
            acc[1][c] = MFMA16(a[1], b, acc[1][c]);
        }
    }
    #pragma unroll
    for (int c = 0; c < 8; ++c) {
        float ob = Ob[c * 16 + r16];
        float cs = 0.f, cq = 0.f;
        #pragma unroll
        for (int rt = 0; rt < 2; ++rt)
            #pragma unroll
            for (int j = 0; j < 4; ++j) {
                int row = rowbase + rt * 16 + g16 * 4 + j;
                size_t idx = (size_t)row * DD + c * 16 + r16;
                float tv = h[idx] + acc[rt][c][j] + ob;
                tbuf[idx] = tv;
                cs += tv; cq += tv * tv;
            }
        cs += __shfl_xor(cs, 16); cs += __shfl_xor(cs, 32);
        cq += __shfl_xor(cq, 16); cq += __shfl_xor(cq, 32);
        if (g16 == 0) {
            sred[w * 128 + c * 16 + r16] = cs;
            qred[w * 128 + c * 16 + r16] = cq;
        }
    }
    __syncthreads();
    if (t < 128) {
        float s = 0.f, q = 0.f;
        #pragma unroll
        for (int ww = 0; ww < 4; ++ww) { s += sred[ww * 128 + t]; q += qred[ww * 128 + t]; }
        atomicAdd(&bnsum[t], s);
        atomicAdd(&bnsq[t], q);
    }
}

// ---------------------------------------------------------------------------
// K4: u = relu(bn1(t) @ F1W + F1b) as bf16 [N,256].
// 8 waves: (rowtile of 32) x (coltile of 128). bn1 applied on the fly.
// ---------------------------------------------------------------------------
__global__ __launch_bounds__(512) void k_ffn1(const float* __restrict__ tbuf,
                                              const short* __restrict__ f1wb,
                                              const float* __restrict__ F1b,
                                              const float* __restrict__ bn_g,
                                              const float* __restrict__ bn_b,
                                              const float* __restrict__ bnsum,
                                              const float* __restrict__ bnsq,
                                              short* __restrict__ u) {
    const int t = threadIdx.x, w = t >> 6, l = t & 63;
    const int g16 = l >> 4, r16 = l & 15;
    const int ct = w & 1, rw = w >> 1;
    const int rowbase = blockIdx.x * 128 + rw * 32;
    const float inv = 1.f / NN;
    f32x4 acc[2][8];
    #pragma unroll
    for (int rt = 0; rt < 2; ++rt)
        #pragma unroll
        for (int c = 0; c < 8; ++c) acc[rt][c] = (f32x4){0.f, 0.f, 0.f, 0.f};
    for (int s = 0; s < 4; ++s) {
        int k0 = s * 32 + g16 * 8;
        float4 s0 = *(const float4*)(bnsum + k0), s1 = *(const float4*)(bnsum + k0 + 4);
        float4 q0 = *(const float4*)(bnsq + k0),  q1 = *(const float4*)(bnsq + k0 + 4);
        float4 gg0 = *(const float4*)(bn_g + k0), gg1 = *(const float4*)(bn_g + k0 + 4);
        float4 bb0 = *(const float4*)(bn_b + k0), bb1 = *(const float4*)(bn_b + k0 + 4);
        float sm[8] = {s0.x, s0.y, s0.z, s0.w, s1.x, s1.y, s1.z, s1.w};
        float sq[8] = {q0.x, q0.y, q0.z, q0.w, q1.x, q1.y, q1.z, q1.w};
        float gm[8] = {gg0.x, gg0.y, gg0.z, gg0.w, gg1.x, gg1.y, gg1.z, gg1.w};
        float bt[8] = {bb0.x, bb0.y, bb0.z, bb0.w, bb1.x, bb1.y, bb1.z, bb1.w};
        float scv[8], shv[8];
        #pragma unroll
        for (int j = 0; j < 8; ++j) {
            float mu = sm[j] * inv;
            float var = sq[j] * inv - mu * mu;
            scv[j] = gm[j] * rsqrtf(var + EPSV);
            shv[j] = bt[j] - mu * scv[j];
        }
        bf16x8 a[2];
        #pragma unroll
        for (int rt = 0; rt < 2; ++rt) {
            int row = rowbase + rt * 16 + r16;
            const float* tp = tbuf + (size_t)row * DD + k0;
            float4 x0 = *(const float4*)tp, x1 = *(const float4*)(tp + 4);
            float v[8] = {x0.x, x0.y, x0.z, x0.w, x1.x, x1.y, x1.z, x1.w};
            bf16x8 af;
            #pragma unroll
            for (int j = 0; j < 8; ++j) af[j] = (short)f2bf(v[j] * scv[j] + shv[j]);
            a[rt] = af;
        }
        #pragma unroll
        for (int cc = 0; cc < 8; ++cc) {
            int c = ct * 8 + cc;
            bf16x8 b = *(const bf16x8*)(f1wb + ((size_t)(s * 16 + c) * 64 + l) * 8);
            acc[0][cc] = MFMA16(a[0], b, acc[0][cc]);
            acc[1][cc] = MFMA16(a[1], b, acc[1][cc]);
        }
    }
    #pragma unroll
    for (int rt = 0; rt < 2; ++rt)
        #pragma unroll
        for (int cc = 0; cc < 8; ++cc) {
            int col = (ct * 8 + cc) * 16 + r16;
            float fb = F1b[col];
            #pragma unroll
            for (int j = 0; j < 4; ++j) {
                int row = rowbase + rt * 16 + g16 * 4 + j;
                u[(size_t)row * 256 + col] = (short)f2bf(fmaxf(acc[rt][cc][j] + fb, 0.f));
            }
        }
}

// ---------------------------------------------------------------------------
// K5: z = bn1(t) + u @ F2W + F2b (in-place over tbuf); fused bn2 column sums.
// ---------------------------------------------------------------------------
__global__ __launch_bounds__(256) void k_ffn2(const short* __restrict__ u,
                                              const short* __restrict__ f2wb,
                                              const float* __restrict__ F2b,
                                              const float* __restrict__ bn_g,
                                              const float* __restrict__ bn_b,
                                              const float* __restrict__ bnsum,
                                              const float* __restrict__ bnsq,
                                              float* __restrict__ tbuf,
                                              float* __restrict__ bnsum2,
                                              float* __restrict__ bnsq2) {
    __shared__ float sred[4 * 128], qred[4 * 128];
    const int t = threadIdx.x, w = t >> 6, l = t & 63;
    const int g16 = l >> 4, r16 = l & 15;
    const int rowbase = blockIdx.x * 128 + w * 32;
    const float inv = 1.f / NN;
    f32x4 acc[2][8];
    #pragma unroll
    for (int rt = 0; rt < 2; ++rt)
        #pragma unroll
        for (int c = 0; c < 8; ++c) acc[rt][c] = (f32x4){0.f, 0.f, 0.f, 0.f};
    for (int s = 0; s < 8; ++s) {
        bf16x8 a[2];
        #pragma unroll
        for (int rt = 0; rt < 2; ++rt)
            a[rt] = *(const bf16x8*)(u + (size_t)(rowbase + rt * 16 + r16) * 256 + s * 32 + g16 * 8);
        #pragma unroll
        for (int c = 0; c < 8; ++c) {
            bf16x8 b = *(const bf16x8*)(f2wb + ((size_t)(s * 8 + c) * 64 + l) * 8);
            acc[0][c] = MFMA16(a[0], b, acc[0][c]);
            acc[1][c] = MFMA16(a[1], b, acc[1][c]);
        }
    }
    #pragma unroll
    for (int c = 0; c < 8; ++c) {
        int col = c * 16 + r16;
        float mu = bnsum[col] * inv;
        float var = bnsq[col] * inv - mu * mu;
        float sc = bn_g[col] * rsqrtf(var + EPSV);
        float sh = bn_b[col] - mu * sc;
        float fb = F2b[col];
        float cs = 0.f, cq = 0.f;
        #pragma unroll
        for (int rt = 0; rt < 2; ++rt)
            #pragma unroll
            for (int j = 0; j < 4; ++j) {
                int row = rowbase + rt * 16 + g16 * 4 + j;
                size_t idx = (size_t)row * DD + col;
                float x = tbuf[idx] * sc + sh;
                float zv = x + acc[rt][c][j] + fb;
                tbuf[idx] = zv;
                cs += zv; cq += zv * zv;
            }
        cs += __shfl_xor(cs, 16); cs += __shfl_xor(cs, 32);
        cq += __shfl_xor(cq, 16); cq += __shfl_xor(cq, 32);
        if (g16 == 0) {
            sred[w * 128 + col] = cs;
            qred[w * 128 + col] = cq;
        }
    }
    __syncthreads();
    if (t < 128) {
        float s = 0.f, q = 0.f;
        #pragma unroll
        for (int ww = 0; ww < 4; ++ww) { s += sred[ww * 128 + t]; q += qred[ww * 128 + t]; }
        atomicAdd(&bnsum2[t], s);
        atomicAdd(&bnsq2[t], q);
    }
}

// ---------------------------------------------------------------------------
// K6: out = bn2(z) — elementwise, float2 per thread.
// ---------------------------------------------------------------------------
__global__ __launch_bounds__(256) void k_out(const float* __restrict__ z,
                                             const float* __restrict__ bnsum,
                                             const float* __restrict__ bnsq,
                                             const float* __restrict__ gam,
                                             const float* __restrict__ bet,
                                             float* __restrict__ out) {
    int idx = blockIdx.x * 256 + threadIdx.x;  // over N*64 float2's
    int c0 = (idx & 63) * 2;
    const float inv = 1.f / NN;
    float mu0 = bnsum[c0] * inv, mu1 = bnsum[c0 + 1] * inv;
    float v0 = bnsq[c0] * inv - mu0 * mu0, v1 = bnsq[c0 + 1] * inv - mu1 * mu1;
    float sc0 = gam[c0] * rsqrtf(v0 + EPSV), sc1 = gam[c0 + 1] * rsqrtf(v1 + EPSV);
    float sh0 = bet[c0] - mu0 * sc0, sh1 = bet[c0 + 1] - mu1 * sc1;
    float2 zv = ((const float2*)z)[idx];
    float2 ov;
    ov.x = zv.x * sc0 + sh0;
    ov.y = zv.y * sc1 + sh1;
    ((float2*)out)[idx] = ov;
}

// ---------------------------------------------------------------------------
extern "C" void kernel_launch(void* const* d_in, const int* in_sizes, int n_in,
                              void* d_out, int out_size, void* d_ws, size_t ws_size,
                              hipStream_t stream) {
    const float* h    = (const float*)d_in[0];
    const int*   nbr  = (const int*)d_in[1];
    const float* W1   = (const float*)d_in[2];
    const float* b1   = (const float*)d_in[3];
    const float* W2   = (const float*)d_in[4];
    const float* b2   = (const float*)d_in[5];
    const float* OW   = (const float*)d_in[6];
    const float* Ob   = (const float*)d_in[7];
    const float* bn1g = (const float*)d_in[8];
    const float* bn1b = (const float*)d_in[9];
    const float* F1W  = (const float*)d_in[10];
    const float* F1b  = (const float*)d_in[11];
    const float* F2W  = (const float*)d_in[12];
    const float* F2b  = (const float*)d_in[13];
    const float* bn2g = (const float*)d_in[14];
    const float* bn2b = (const float*)d_in[15];
    float* out = (float*)d_out;

    char* wsb = (char*)d_ws;
    // region1 (16 MB): mb bf16 [N,256] -> u bf16 [N,256]
    unsigned short* mb = (unsigned short*)wsb;
    short* u   = (short*)wsb;
    float* tbuf = (float*)(wsb + ((size_t)16 << 20));           // 16 MB fp32
    unsigned short* gb = (unsigned short*)(wsb + ((size_t)32 << 20)); // 8 MB bf16
    char* wtb = wsb + ((size_t)40 << 20);
    short* w1b  = (short*)wtb;                                  // 32 KB
    short* owb  = w1b + 16384;                                  // 64 KB
    short* f1wb = owb + 32768;                                  // 64 KB
    short* f2wb = f1wb + 32768;                                 // 64 KB
    float* stats = (float*)(f2wb + 32768);
    float* bnsum1 = stats;
    float* bnsq1  = stats + 128;
    float* bnsum2 = stats + 256;
    float* bnsq2  = stats + 384;

    k_prep_w4<<<58, 256, 0, stream>>>(W1, OW, F1W, F2W, w1b, owb, f1wb, f2wb, stats);
    k_g<<<NN / 128, 256, 0, stream>>>(h, w1b, gb);
    k_att<<<NN / 4, 256, 0, stream>>>(gb, nbr, b1, W2, b2, h, mb);
    k_t<<<NN / 128, 256, 0, stream>>>((const short*)mb, owb, h, Ob, tbuf, bnsum1, bnsq1);
    k_ffn1<<<NN / 128, 512, 0, stream>>>(tbuf, f1wb, F1b, bn1g, bn1b, bnsum1, bnsq1, u);
    k_ffn2<<<NN / 128, 256, 0, stream>>>(u, f2wb, F2b, bn1g, bn1b, bnsum1, bnsq1,
                                         tbuf, bnsum2, bnsq2);
    k_out<<<NN * 64 / 256, 256, 0, stream>>>(tbuf, bnsum2, bnsq2, bn2g, bn2b, out);
}

// Round 7
// 126.383 us; speedup vs baseline: 4.1776x; 1.0427x over previous
//
#include <hip/hip_runtime.h>
#include <math.h>

#define NN 32768
#define KK 16
#define DD 128
#define EPSV 1e-5f

typedef __attribute__((ext_vector_type(8))) short bf16x8;
typedef __attribute__((ext_vector_type(4))) float f32x4;

__device__ __forceinline__ unsigned short f2bf(float x) {
    unsigned u; __builtin_memcpy(&u, &x, 4);
    u += 0x7fffu + ((u >> 16) & 1u);          // RNE (finite inputs)
    return (unsigned short)(u >> 16);
}
__device__ __forceinline__ float bf2f(unsigned short b) {
    unsigned u = ((unsigned)b) << 16; float f; __builtin_memcpy(&f, &u, 4); return f;
}

#define MFMA16(a, b, c) __builtin_amdgcn_mfma_f32_16x16x32_bf16((a), (b), (c), 0, 0, 0)

// LDS index swizzle for [128][128] bf16 tiles (256 B rows): flip ushort-index
// bits 3..5 with row&7 so K-chunk reads across 16 rows spread over banks.
__device__ __forceinline__ int swz(int row, int col) {
    return row * 128 + (col ^ ((row & 7) << 3));
}

// ---------------------------------------------------------------------------
// Weight prep: 4 weight matrices -> bf16 B-fragment order; also zero stats.
// Frag (s,c,lane l): elems j=0..7 = B[32s + 8*(l>>4) + j][16c + (l&15)],
// stored at out[((s*NT + c)*64 + l)*8 + j].
// ---------------------------------------------------------------------------
__global__ __launch_bounds__(256) void k_prep_w4(const float* __restrict__ W1,
                                                 const float* __restrict__ OW,
                                                 const float* __restrict__ F1W,
                                                 const float* __restrict__ F2W,
                                                 short* __restrict__ w1b,
                                                 short* __restrict__ owb,
                                                 short* __restrict__ f1wb,
                                                 short* __restrict__ f2wb,
                                                 float* __restrict__ stats) {
    int tid = blockIdx.x * 256 + threadIdx.x;
    if (tid >= 14848) return;
    if (tid >= 14336) { stats[tid - 14336] = 0.f; return; }
    const float* W; short* out; int Ncol; int base;
    if (tid < 2048)       { W = W1;  out = w1b;  Ncol = 128; base = 0; }
    else if (tid < 6144)  { W = OW;  out = owb;  Ncol = 128; base = 2048; }
    else if (tid < 10240) { W = F1W; out = f1wb; Ncol = 256; base = 6144; }
    else                  { W = F2W; out = f2wb; Ncol = 128; base = 10240; }
    int t = tid - base;
    int l = t & 63, sc = t >> 6;
    int NT = Ncol >> 4;
    int c = sc % NT, s = sc / NT;
    int col = c * 16 + (l & 15);
    int k0 = s * 32 + (l >> 4) * 8;
    bf16x8 v;
    #pragma unroll
    for (int j = 0; j < 8; ++j) v[j] = (short)f2bf(W[(size_t)(k0 + j) * Ncol + col]);
    *(bf16x8*)(out + (size_t)t * 8) = v;
}

// ---------------------------------------------------------------------------
// K1: gb = bf16(h @ W1). 4 waves x 32 rows, 256 blocks, no LDS.
// ---------------------------------------------------------------------------
__global__ __launch_bounds__(256) void k_g(const float* __restrict__ h,
                                           const short* __restrict__ w1b,
                                           unsigned short* __restrict__ gb) {
    const int t = threadIdx.x, w = t >> 6, l = t & 63;
    const int g16 = l >> 4, r16 = l & 15;
    const int rowbase = blockIdx.x * 128 + w * 32;
    f32x4 acc[2][8];
    #pragma unroll
    for (int rt = 0; rt < 2; ++rt)
        #pragma unroll
        for (int c = 0; c < 8; ++c) acc[rt][c] = (f32x4){0.f, 0.f, 0.f, 0.f};
    for (int s = 0; s < 4; ++s) {
        bf16x8 a[2];
        #pragma unroll
        for (int rt = 0; rt < 2; ++rt) {
            int row = rowbase + rt * 16 + r16;
            const float* hp = h + (size_t)row * DD + s * 32 + g16 * 8;
            float4 x0 = *(const float4*)hp;
            float4 x1 = *(const float4*)(hp + 4);
            bf16x8 af;
            af[0] = (short)f2bf(x0.x); af[1] = (short)f2bf(x0.y);
            af[2] = (short)f2bf(x0.z); af[3] = (short)f2bf(x0.w);
            af[4] = (short)f2bf(x1.x); af[5] = (short)f2bf(x1.y);
            af[6] = (short)f2bf(x1.z); af[7] = (short)f2bf(x1.w);
            a[rt] = af;
        }
        #pragma unroll
        for (int c = 0; c < 8; ++c) {
            bf16x8 b = *(const bf16x8*)(w1b + ((size_t)(s * 8 + c) * 64 + l) * 8);
            acc[0][c] = MFMA16(a[0], b, acc[0][c]);
            acc[1][c] = MFMA16(a[1], b, acc[1][c]);
        }
    }
    #pragma unroll
    for (int rt = 0; rt < 2; ++rt)
        #pragma unroll
        for (int c = 0; c < 8; ++c)
            #pragma unroll
            for (int j = 0; j < 4; ++j) {
                int row = rowbase + rt * 16 + g16 * 4 + j;
                gb[(size_t)row * DD + c * 16 + r16] = f2bf(acc[rt][c][j]);
            }
}

// ---------------------------------------------------------------------------
// K2: per-node attention stats + mb write. One wave per node.
// ---------------------------------------------------------------------------
__global__ __launch_bounds__(256) void k_att(const unsigned short* __restrict__ gb,
                                             const int* __restrict__ nbr,
                                             const float* __restrict__ b1,
                                             const float* __restrict__ W2,
                                             const float* __restrict__ b2,
                                             const float* __restrict__ h,
                                             unsigned short* __restrict__ mb) {
    const int t = threadIdx.x;
    const int w = t >> 6, lane = t & 63;
    const int node = blockIdx.x * 4 + w;
    ushort2 gdv = ((const ushort2*)(gb + (size_t)node * DD))[lane];
    const float gdx = bf2f(gdv.x), gdy = bf2f(gdv.y);
    const float2 b1v = ((const float2*)b1)[lane];
    const float2 w2v = ((const float2*)W2)[lane];
    const float b2s = b2[0];
    float asum = 0.f, amx = -1e30f, amn = 1e30f;
    #pragma unroll
    for (int k = 0; k < KK; ++k) {
        int src = nbr[node * KK + k];
        ushort2 gsv = ((const ushort2*)(gb + (size_t)src * DD))[lane];
        float v = fmaxf(bf2f(gsv.x) - gdx + b1v.x, 0.f) * w2v.x
                + fmaxf(bf2f(gsv.y) - gdy + b1v.y, 0.f) * w2v.y;
        #pragma unroll
        for (int off = 32; off > 0; off >>= 1) v += __shfl_xor(v, off);
        float s = fmaxf(v + b2s, 0.f);
        float att = __expf(-s);
        asum += att;
        amx = fmaxf(amx, att);
        amn = fminf(amn, att);
    }
    const float am = asum * (1.f / KK);
    float2 hv = ((const float2*)(h + (size_t)node * DD))[lane];
    ushort2 m0, m1;
    m0.x = f2bf(am * hv.x);
    m0.y = f2bf(am * hv.y);
    m1.x = f2bf((hv.x >= 0.f ? amx : amn) * hv.x);
    m1.y = f2bf((hv.y >= 0.f ? amx : amn) * hv.y);
    ((ushort2*)(mb + (size_t)node * 256))[lane] = m0;
    ((ushort2*)(mb + (size_t)node * 256 + 128))[lane] = m1;
}

// ---------------------------------------------------------------------------
// K3: t = h + mb @ OW + Ob; t stored BF16; fused bn1 column sums (from fp32).
// ---------------------------------------------------------------------------
__global__ __launch_bounds__(256) void k_t(const short* __restrict__ mb,
                                           const short* __restrict__ owb,
                                           const float* __restrict__ h,
                                           const float* __restrict__ Ob,
                                           unsigned short* __restrict__ tb,
                                           float* __restrict__ bnsum,
                                           float* __restrict__ bnsq) {
    __shared__ float sred[4 * 128], qred[4 * 128];
    const int t = threadIdx.x, w = t >> 6, l = t & 63;
    const int g16 = l >> 4, r16 = l & 15;
    const int rowbase = blockIdx.x * 128 + w * 32;
    f32x4 acc[2][8];
    #pragma unroll
    for (int rt = 0; rt < 2; ++rt)
        #pragma unroll
        for (int c = 0; c < 8; ++c) acc[rt][c] = (f32x4){0.f, 0.f, 0.f, 0.f};
    for (int s = 0; s < 8; ++s) {
        bf16x8 a[2];
        #pragma unroll
        for (int rt = 0; rt < 2; ++rt)
            a[rt] = *(const bf16x8*)(mb + (size_t)(rowbase + rt * 16 + r16) * 256 + s * 32 + g16 * 8);
        #pragma unroll
        for (int c = 0; c < 8; ++c) {
            bf16x8 b = *(const bf16x8*)(owb + ((size_t)(s * 8 + c) * 64 + l) * 8);
            acc[0][c] = MFMA16(a[0], b, acc[0][c]);
            acc[1][c] = MFMA16(a[1], b, acc[1][c]);
        }
    }
    #pragma unroll
    for (int c = 0; c < 8; ++c) {
        int col = c * 16 + r16;
        float ob = Ob[col];
        float cs = 0.f, cq = 0.f;
        #pragma unroll
        for (int rt = 0; rt < 2; ++rt)
            #pragma unroll
            for (int j = 0; j < 4; ++j) {
                int row = rowbase + rt * 16 + g16 * 4 + j;
                size_t idx = (size_t)row * DD + col;
                float tv = h[idx] + acc[rt][c][j] + ob;
                tb[idx] = f2bf(tv);
                cs += tv; cq += tv * tv;
            }
        cs += __shfl_xor(cs, 16); cs += __shfl_xor(cs, 32);
        cq += __shfl_xor(cq, 16); cq += __shfl_xor(cq, 32);
        if (g16 == 0) { sred[w * 128 + col] = cs; qred[w * 128 + col] = cq; }
    }
    __syncthreads();
    if (t < 128) {
        float s = 0.f, q = 0.f;
        #pragma unroll
        for (int ww = 0; ww < 4; ++ww) { s += sred[ww * 128 + t]; q += qred[ww * 128 + t]; }
        atomicAdd(&bnsum[t], s);
        atomicAdd(&bnsq[t], q);
    }
}

// ---------------------------------------------------------------------------
// K4: fused FFN1+FFN2 per 128-row block:
//   stage t (bf16) -> LDS; per column-half: x=bn1(t) A-frags -> u half in LDS
//   -> acc2 += u @ F2W-half.  Epilogue: z = x + acc2 + F2b (fp32 to global),
//   fused bn2 column sums.  u never touches HBM.
// ---------------------------------------------------------------------------
__global__ __launch_bounds__(256) void k_ffn12(const unsigned short* __restrict__ tb,
                                               const short* __restrict__ f1wb,
                                               const float* __restrict__ F1b,
                                               const short* __restrict__ f2wb,
                                               const float* __restrict__ F2b,
                                               const float* __restrict__ bn1g,
                                               const float* __restrict__ bn1b,
                                               const float* __restrict__ bnsum1,
                                               const float* __restrict__ bnsq1,
                                               float* __restrict__ z,
                                               float* __restrict__ bnsum2,
                                               float* __restrict__ bnsq2) {
    __shared__ unsigned short t_lds[128 * 128];   // 32 KB
    __shared__ unsigned short u_lds[128 * 128];   // 32 KB (one column-half)
    __shared__ float sred[4 * 128], qred[4 * 128];

    const int t = threadIdx.x, w = t >> 6, l = t & 63;
    const int g16 = l >> 4, r16 = l & 15;
    const int brow = w * 32;
    const int growb = blockIdx.x * 128;
    const float inv = 1.f / NN;

    // stage this wave's 32 t-rows into LDS (swizzled)
    #pragma unroll
    for (int i = 0; i < 8; ++i) {
        int lr = brow + i * 4 + g16;
        int col = r16 * 8;
        bf16x8 v = *(const bf16x8*)(tb + (size_t)(growb + lr) * DD + col);
        *(bf16x8*)&t_lds[swz(lr, col)] = v;
    }
    __syncthreads();

    f32x4 acc2[2][8];
    #pragma unroll
    for (int rt = 0; rt < 2; ++rt)
        #pragma unroll
        for (int c = 0; c < 8; ++c) acc2[rt][c] = (f32x4){0.f, 0.f, 0.f, 0.f};

    #pragma unroll 1
    for (int ct = 0; ct < 2; ++ct) {
        f32x4 acc1[2][8];
        #pragma unroll
        for (int rt = 0; rt < 2; ++rt)
            #pragma unroll
            for (int c = 0; c < 8; ++c) acc1[rt][c] = (f32x4){0.f, 0.f, 0.f, 0.f};
        for (int s = 0; s < 4; ++s) {
            int k0 = s * 32 + g16 * 8;
            float4 s0 = *(const float4*)(bnsum1 + k0), s1 = *(const float4*)(bnsum1 + k0 + 4);
            float4 q0 = *(const float4*)(bnsq1 + k0),  q1 = *(const float4*)(bnsq1 + k0 + 4);
            float4 gg0 = *(const float4*)(bn1g + k0),  gg1 = *(const float4*)(bn1g + k0 + 4);
            float4 bb0 = *(const float4*)(bn1b + k0),  bb1 = *(const float4*)(bn1b + k0 + 4);
            float sm[8] = {s0.x, s0.y, s0.z, s0.w, s1.x, s1.y, s1.z, s1.w};
            float sq[8] = {q0.x, q0.y, q0.z, q0.w, q1.x, q1.y, q1.z, q1.w};
            float gm[8] = {gg0.x, gg0.y, gg0.z, gg0.w, gg1.x, gg1.y, gg1.z, gg1.w};
            float bt[8] = {bb0.x, bb0.y, bb0.z, bb0.w, bb1.x, bb1.y, bb1.z, bb1.w};
            bf16x8 a[2];
            #pragma unroll
            for (int rt = 0; rt < 2; ++rt) {
                int lr = brow + rt * 16 + r16;
                bf16x8 tv8 = *(const bf16x8*)&t_lds[swz(lr, k0)];
                bf16x8 af;
                #pragma unroll
                for (int j = 0; j < 8; ++j) {
                    float mu = sm[j] * inv;
                    float var = sq[j] * inv - mu * mu;
                    float scv = gm[j] * rsqrtf(var + EPSV);
                    float shv = bt[j] - mu * scv;
                    af[j] = (short)f2bf(bf2f((unsigned short)tv8[j]) * scv + shv);
                }
                a[rt] = af;
            }
            #pragma unroll
            for (int cc = 0; cc < 8; ++cc) {
                int c = ct * 8 + cc;
                bf16x8 b = *(const bf16x8*)(f1wb + ((size_t)(s * 16 + c) * 64 + l) * 8);
                acc1[0][cc] = MFMA16(a[0], b, acc1[0][cc]);
                acc1[1][cc] = MFMA16(a[1], b, acc1[1][cc]);
            }
        }
        // write u half into LDS
        #pragma unroll
        for (int cc = 0; cc < 8; ++cc) {
            int colh = cc * 16 + r16;
            float fb = F1b[ct * 128 + colh];
            #pragma unroll
            for (int rt = 0; rt < 2; ++rt)
                #pragma unroll
                for (int j = 0; j < 4; ++j) {
                    int lr = brow + rt * 16 + g16 * 4 + j;
                    u_lds[swz(lr, colh)] = f2bf(fmaxf(acc1[rt][cc][j] + fb, 0.f));
                }
        }
        __syncthreads();
        // FFN2 partial over this K-half
        for (int s2 = 0; s2 < 4; ++s2) {
            int k0h = s2 * 32 + g16 * 8;
            bf16x8 a2[2];
            #pragma unroll
            for (int rt = 0; rt < 2; ++rt) {
                int lr = brow + rt * 16 + r16;
                a2[rt] = *(const bf16x8*)&u_lds[swz(lr, k0h)];
            }
            int sg = ct * 4 + s2;
            #pragma unroll
            for (int c = 0; c < 8; ++c) {
                bf16x8 b = *(const bf16x8*)(f2wb + ((size_t)(sg * 8 + c) * 64 + l) * 8);
                acc2[0][c] = MFMA16(a2[0], b, acc2[0][c]);
                acc2[1][c] = MFMA16(a2[1], b, acc2[1][c]);
            }
        }
        __syncthreads();  // protect u_lds WAR before next half
    }

    // epilogue: z = bn1(t) + acc2 + F2b; bn2 column sums
    #pragma unroll
    for (int c = 0; c < 8; ++c) {
        int col = c * 16 + r16;
        float mu = bnsum1[col] * inv;
        float var = bnsq1[col] * inv - mu * mu;
        float sc = bn1g[col] * rsqrtf(var + EPSV);
        float sh = bn1b[col] - mu * sc;
        float fb = F2b[col];
        float cs = 0.f, cq = 0.f;
        #pragma unroll
        for (int rt = 0; rt < 2; ++rt)
            #pragma unroll
            for (int j = 0; j < 4; ++j) {
                int lr = brow + rt * 16 + g16 * 4 + j;
                float xv = bf2f(t_lds[swz(lr, col)]) * sc + sh;
                float zv = xv + acc2[rt][c][j] + fb;
                z[(size_t)(growb + lr) * DD + col] = zv;
                cs += zv; cq += zv * zv;
            }
        cs += __shfl_xor(cs, 16); cs += __shfl_xor(cs, 32);
        cq += __shfl_xor(cq, 16); cq += __shfl_xor(cq, 32);
        if (g16 == 0) { sred[w * 128 + col] = cs; qred[w * 128 + col] = cq; }
    }
    __syncthreads();
    if (t < 128) {
        float s = 0.f, q = 0.f;
        #pragma unroll
        for (int ww = 0; ww < 4; ++ww) { s += sred[ww * 128 + t]; q += qred[ww * 128 + t]; }
        atomicAdd(&bnsum2[t], s);
        atomicAdd(&bnsq2[t], q);
    }
}

// ---------------------------------------------------------------------------
// K5: out = bn2(z) — elementwise, float2 per thread.
// ---------------------------------------------------------------------------
__global__ __launch_bounds__(256) void k_out(const float* __restrict__ z,
                                             const float* __restrict__ bnsum,
                                             const float* __restrict__ bnsq,
                                             const float* __restrict__ gam,
                                             const float* __restrict__ bet,
                                             float* __restrict__ out) {
    int idx = blockIdx.x * 256 + threadIdx.x;  // over N*64 float2's
    int c0 = (idx & 63) * 2;
    const float inv = 1.f / NN;
    float mu0 = bnsum[c0] * inv, mu1 = bnsum[c0 + 1] * inv;
    float v0 = bnsq[c0] * inv - mu0 * mu0, v1 = bnsq[c0 + 1] * inv - mu1 * mu1;
    float sc0 = gam[c0] * rsqrtf(v0 + EPSV), sc1 = gam[c0 + 1] * rsqrtf(v1 + EPSV);
    float sh0 = bet[c0] - mu0 * sc0, sh1 = bet[c0 + 1] - mu1 * sc1;
    float2 zv = ((const float2*)z)[idx];
    float2 ov;
    ov.x = zv.x * sc0 + sh0;
    ov.y = zv.y * sc1 + sh1;
    ((float2*)out)[idx] = ov;
}

// ---------------------------------------------------------------------------
extern "C" void kernel_launch(void* const* d_in, const int* in_sizes, int n_in,
                              void* d_out, int out_size, void* d_ws, size_t ws_size,
                              hipStream_t stream) {
    const float* h    = (const float*)d_in[0];
    const int*   nbr  = (const int*)d_in[1];
    const float* W1   = (const float*)d_in[2];
    const float* b1   = (const float*)d_in[3];
    const float* W2   = (const float*)d_in[4];
    const float* b2   = (const float*)d_in[5];
    const float* OW   = (const float*)d_in[6];
    const float* Ob   = (const float*)d_in[7];
    const float* bn1g = (const float*)d_in[8];
    const float* bn1b = (const float*)d_in[9];
    const float* F1W  = (const float*)d_in[10];
    const float* F1b  = (const float*)d_in[11];
    const float* F2W  = (const float*)d_in[12];
    const float* F2b  = (const float*)d_in[13];
    const float* bn2g = (const float*)d_in[14];
    const float* bn2b = (const float*)d_in[15];
    float* out = (float*)d_out;

    char* wsb = (char*)d_ws;
    unsigned short* mb = (unsigned short*)wsb;                        // 16 MB
    unsigned short* gb = (unsigned short*)(wsb + ((size_t)16 << 20)); // 8 MB
    unsigned short* tb = (unsigned short*)(wsb + ((size_t)24 << 20)); // 8 MB bf16
    float* zbuf = (float*)(wsb + ((size_t)32 << 20));                 // 16 MB
    char* wtb = wsb + ((size_t)48 << 20);
    short* w1b  = (short*)wtb;                                        // 32 KB
    short* owb  = w1b + 16384;                                        // 64 KB
    short* f1wb = owb + 32768;                                        // 64 KB
    short* f2wb = f1wb + 32768;                                       // 64 KB
    float* stats = (float*)(f2wb + 32768);
    float* bnsum1 = stats;
    float* bnsq1  = stats + 128;
    float* bnsum2 = stats + 256;
    float* bnsq2  = stats + 384;

    k_prep_w4<<<58, 256, 0, stream>>>(W1, OW, F1W, F2W, w1b, owb, f1wb, f2wb, stats);
    k_g<<<NN / 128, 256, 0, stream>>>(h, w1b, gb);
    k_att<<<NN / 4, 256, 0, stream>>>(gb, nbr, b1, W2, b2, h, mb);
    k_t<<<NN / 128, 256, 0, stream>>>((const short*)mb, owb, h, Ob, tb, bnsum1, bnsq1);
    k_ffn12<<<NN / 128, 256, 0, stream>>>(tb, f1wb, F1b, f2wb, F2b, bn1g, bn1b,
                                          bnsum1, bnsq1, zbuf, bnsum2, bnsq2);
    k_out<<<NN * 64 / 256, 256, 0, stream>>>(zbuf, bnsum2, bnsq2, bn2g, bn2b, out);
}